// Round 6
// baseline (276.636 us; speedup 1.0000x reference)
//
#include <hip/hip_runtime.h>
#include <math.h>

// B=8, L=32, H=1024, N=32
// ws layout (floats):
#define NODE_OFF   0          // 8192*32
#define CN_OFF     262144     // 8192*32 (diag rows used by chain init)
#define SPAN_OFF   524288     // 8192
#define D_OFF      532480     // 256*32
#define RBF_OFF    540672     // 32768 halfs: frag-order bf16 exp(rules)
#define PART_OFF   557056     // 4*262144
#define PARTS_OFF  1605632    // 4*8192

typedef short bf16x8 __attribute__((ext_vector_type(8)));
typedef float f32x16 __attribute__((ext_vector_type(16)));

union BFU { unsigned u[4]; bf16x8 v; };

__device__ inline short f2bf(float f) {
  union { float f; unsigned u; } v; v.f = f;
  unsigned r = (v.u + 0x7FFFu + ((v.u >> 16) & 1u)) >> 16;
  return (short)r;
}

__device__ __forceinline__ unsigned pk2bf(float lo, float hi) {
  unsigned r;
  asm("v_cvt_pk_bf16_f32 %0, %1, %2" : "=v"(r) : "v"(lo), "v"(hi));
  return r;
}

// Fused front kernel, 896 blocks x 256:
//  0..511: node split-K GEMM   512..767: posnode+D   768..895: Rbf swizzle
__global__ __launch_bounds__(256) void k_pre(
    const float* __restrict__ ph, const float* __restrict__ Wn,
    const float* __restrict__ Ws, const float* __restrict__ sh,
    const float* __restrict__ Wp, const float* __restrict__ bp,
    const float* __restrict__ pmask, const float* __restrict__ pu,
    const float* __restrict__ pum, const float* __restrict__ rs,
    const float* __restrict__ rm, float* __restrict__ part,
    float* __restrict__ partS, float* __restrict__ D,
    unsigned short* __restrict__ Rbf) {
  __shared__ float smem[12672];
  int t = threadIdx.x;
  int bid = blockIdx.x;
  if (bid >= 768) {   // ---- Rbf: frag-order bf16 of exp(masked rules) ----
    int idx = ((bid - 768) << 8) + t;        // [kst(64)][lane(64)][r(8)]
    int kst = idx >> 9, ln = (idx >> 3) & 63, r = idx & 7;
    int a = ln & 31;
    int kp = kst * 16 + ((ln >> 5) << 3) + r;   // k' = p*32+q
    float v = __expf(rs[a * 1024 + kp] + (rm[a * 1024 + kp] - 1.0f) * 1e10f);
    Rbf[idx] = (unsigned short)f2bf(v);
    return;
  }
  if (bid >= 512) {   // ---- posnode + D ----
    float* rowl = smem;
    float* partl = smem + 1024;
    float* posn = smem + 1288;
    int row = bid - 512;
#pragma unroll
    for (int k = 0; k < 4; ++k) rowl[t + 256 * k] = sh[row * 1024 + t + 256 * k];
    __syncthreads();
    int c = t & 31, seg = t >> 5;
    float pacc = 0.f;
    for (int hh = 0; hh < 128; ++hh)
      pacc += rowl[seg * 128 + hh] * Wp[(seg * 128 + hh) * 32 + c];
    partl[seg * 33 + c] = pacc;
    __syncthreads();
    if (t < 32) {
      float s = 0.f;
#pragma unroll
      for (int k = 0; k < 8; ++k) s += partl[k * 33 + t];
      posn[t] = s + bp[t] + (pmask[t] - 1.0f) * 1e10f;
    }
    __syncthreads();
    if (t < 32) {
      float mq = posn[t];
#pragma unroll
      for (int m = 16; m >= 1; m >>= 1) mq = fmaxf(mq, __shfl_xor(mq, m, 32));
      float sum = 0.f;
#pragma unroll 8
      for (int q = 0; q < 32; ++q)
        sum += __expf(pu[t * 32 + q] + (pum[t * 32 + q] - 1.0f) * 1e15f + posn[q] - mq);
      D[row * 32 + t] = mq + __logf(sum);
    }
    return;
  }
  // ---- node split-K GEMM ----
  float (*A)[132] = (float(*)[132])smem;
  float (*Wl)[32] = (float(*)[32])(smem + 8448);
  float* Wsl = smem + 12544;
  int rg = bid >> 2;
  int s = bid & 3;
  int row0 = rg * 64;
  int h0 = s * 256;
  int tr = t >> 3, tc = t & 7;
  int r0 = tr * 2;
  int c = tc * 4;
  float acc[8] = {0.f, 0.f, 0.f, 0.f, 0.f, 0.f, 0.f, 0.f};
  float sp0 = 0.f, sp1 = 0.f;
  for (int hc = 0; hc < 2; ++hc) {
    int hb = h0 + hc * 128;
#pragma unroll
    for (int k = 0; k < 32; ++k) {
      int f = t + 256 * k;
      int rr = f >> 7, hh = f & 127;
      A[rr][hh] = ph[(row0 + rr) * 1024 + hb + hh];
    }
#pragma unroll
    for (int k = 0; k < 16; ++k) {
      int f = t + 256 * k;
      int hh = f >> 5, cc = f & 31;
      Wl[hh][cc] = Wn[(hb + hh) * 32 + cc];
    }
    if (t < 128) Wsl[t] = Ws[hb + t];
    __syncthreads();
#pragma unroll 2
    for (int h = 0; h < 128; ++h) {
      float a0 = A[r0][h], a1 = A[r0 + 1][h];
      float4 w = *(const float4*)&Wl[h][c];
      acc[0] += a0 * w.x; acc[1] += a0 * w.y; acc[2] += a0 * w.z; acc[3] += a0 * w.w;
      acc[4] += a1 * w.x; acc[5] += a1 * w.y; acc[6] += a1 * w.z; acc[7] += a1 * w.w;
      if (tc == 0) { float wv = Wsl[h]; sp0 += a0 * wv; sp1 += a1 * wv; }
    }
    __syncthreads();
  }
  int row = row0 + r0;
  float* po = part + s * 262144;
  *(float4*)&po[row * 32 + c] = make_float4(acc[0], acc[1], acc[2], acc[3]);
  *(float4*)&po[(row + 1) * 32 + c] = make_float4(acc[4], acc[5], acc[6], acc[7]);
  if (tc == 0) {
    partS[s * 8192 + row] = sp0;
    partS[s * 8192 + row + 1] = sp1;
  }
}

__global__ __launch_bounds__(256) void k_node_reduce(
    const float* __restrict__ part, const float* __restrict__ partS,
    const float* __restrict__ bn, const float* __restrict__ bs,
    const float* __restrict__ D, float* __restrict__ node,
    float* __restrict__ cng, float* __restrict__ span) {
  int t = threadIdx.x;
  int row = blockIdx.x * 8 + (t >> 5);
  int c = t & 31;
  float v = bn[c];
#pragma unroll
  for (int s = 0; s < 4; ++s) v += part[s * 262144 + row * 32 + c];
  node[row * 32 + c] = v;
  int l = (row >> 5) & 31, m = row & 31;
  if (l == m)
    cng[row * 32 + c] = v + D[(row >> 5) * 32 + c] + v;   // chart_diag + node
  if (c == 0) {
    float sp = bs[0];
#pragma unroll
    for (int s = 0; s < 4; ++s) sp += partS[s * 8192 + row];
    span[row] = sp;
  }
}

// ---- chain helpers ----
__device__ __forceinline__ void p2_cell(
    int cg, int slot, int i, int ln, const float* cn, const float* Tbet,
    const int* Tla, const int* Tra, const float* G, unsigned short* Sbf) {
  int pq = ln & 31;
  int jb = (ln >> 5) << 3;
  float Gc = G[cg];
  int base = cg << 5;
  f32x16 Sacc = {};
  {
    BFU ua, ub;
#pragma unroll
    for (int rp = 0; rp < 4; ++rp) {
      float e0 = 0.f, e1 = 0.f, h0 = 0.f, h1 = 0.f;
      int j0 = jb + rp * 2;
      if (j0 < i) {
        float bet = Tbet[base + j0];
        e0 = __expf(cn[Tla[base + j0] + pq] + bet - Gc);
        h0 = __expf(cn[Tra[base + j0] + pq] - bet);
      }
      if (j0 + 1 < i) {
        float bet = Tbet[base + j0 + 1];
        e1 = __expf(cn[Tla[base + j0 + 1] + pq] + bet - Gc);
        h1 = __expf(cn[Tra[base + j0 + 1] + pq] - bet);
      }
      ua.u[rp] = pk2bf(e0, e1);
      ub.u[rp] = pk2bf(h0, h1);
    }
    Sacc = __builtin_amdgcn_mfma_f32_32x32x16_bf16(ua.v, ub.v, Sacc, 0, 0, 0);
  }
  if (i > 16) {
    BFU ua, ub;
#pragma unroll
    for (int rp = 0; rp < 4; ++rp) {
      float e0 = 0.f, e1 = 0.f, h0 = 0.f, h1 = 0.f;
      int j0 = 16 + jb + rp * 2;
      if (j0 < i) {
        float bet = Tbet[base + j0];
        e0 = __expf(cn[Tla[base + j0] + pq] + bet - Gc);
        h0 = __expf(cn[Tra[base + j0] + pq] - bet);
      }
      if (j0 + 1 < i) {
        float bet = Tbet[base + j0 + 1];
        e1 = __expf(cn[Tla[base + j0 + 1] + pq] + bet - Gc);
        h1 = __expf(cn[Tra[base + j0 + 1] + pq] - bet);
      }
      ua.u[rp] = pk2bf(e0, e1);
      ub.u[rp] = pk2bf(h0, h1);
    }
    Sacc = __builtin_amdgcn_mfma_f32_32x32x16_bf16(ua.v, ub.v, Sacc, 0, 0, 0);
  }
  // store S[p][q] bf16 (C/D: col=lane&31, row=(reg&3)+8*(reg>>2)+4*(lane>>5))
  unsigned short* sb = Sbf + slot * 1032;
  int q = ln & 31, hi = (ln >> 5) << 2;
#pragma unroll
  for (int rr = 0; rr < 16; rr += 2) {
    int p = (rr & 3) + ((rr >> 2) << 3) + hi;
    unsigned pk = pk2bf(Sacc[rr], Sacc[rr + 1]);
    sb[p * 32 + q] = (unsigned short)pk;
    sb[(p + 1) * 32 + q] = (unsigned short)(pk >> 16);
  }
}

__device__ __forceinline__ void p3_mat(
    int w, int ln, const unsigned short* Rbf, const unsigned short* Sbf,
    float* slots) {
  if (w < 4) {
    f32x16 C = {};
#pragma unroll
    for (int tt = 0; tt < 16; ++tt) {
      int kst = (w << 4) + tt;
      bf16x8 ra = *(const bf16x8*)(Rbf + (kst << 9) + (ln << 3));
      bf16x8 sbv = *(const bf16x8*)(Sbf + (ln & 15) * 1032 + (kst << 4) + ((ln >> 5) << 3));
      C = __builtin_amdgcn_mfma_f32_32x32x16_bf16(ra, sbv, C, 0, 0, 0);
    }
    float* sl = slots + (w << 10);
#pragma unroll
    for (int rr = 0; rr < 16; ++rr) sl[(rr << 6) + ln] = C[rr];
  }
}

__device__ __forceinline__ void out_cell(
    int g, int i, int nT, int w, int ln, int aoR, int coR,
    const float* slots, const float* G, float nv, float sv, float* cn) {
  int cellg = g * 16 + (coR & 15);
  float pt = slots[(w << 6) + ln] + slots[1024 + (w << 6) + ln] +
             slots[2048 + (w << 6) + ln] + slots[3072 + (w << 6) + ln];
  if (coR < 16 && cellg < nT) {
    float v = G[cellg] + __logf(pt) + nv + sv;
    cn[(cellg * (65 - cellg) / 2 + i) * 33 + aoR] = v + nv;
  }
}

// One block per batch; whole CKY chain in LDS; MFMA for S and rule-matvec.
// Dynamic LDS 133632 B:
//   cn    f32[528*33]  @0       Sbf u16[16*1032] @69696   slots f32[4096] @102720
//   Tbet  f32[1024]    @119104  Tla i32[1024] @123200     Tra i32[1024] @127296
//   maxv  f32[528]     @131392  G f32[32] @133504
__global__ __launch_bounds__(1024, 4) void k_chain2(
    const float* __restrict__ node, const float* __restrict__ span,
    const float* __restrict__ cng, const unsigned short* __restrict__ Rbf,
    const int* __restrict__ sm, const float* __restrict__ rootm,
    float* __restrict__ out) {
  extern __shared__ char lds[];
  float* cn = (float*)lds;
  unsigned short* Sbf = (unsigned short*)(lds + 69696);
  float* slots = (float*)(lds + 102720);
  float* Tbet = (float*)(lds + 119104);
  int* Tla = (int*)(lds + 123200);
  int* Tra = (int*)(lds + 127296);
  float* maxv = (float*)(lds + 131392);
  float* G = (float*)(lds + 133504);
  int t = threadIdx.x;
  int b = blockIdx.x;
  int w = t >> 6;
  int ln = t & 63;
  int rowB = b * 32;
  int aoR = (w & 3) + ((w >> 2) << 3) + ((ln >> 5) << 2);
  int coR = ln & 31;
  // ---- init: diagonal cells ----
  {
    int l = t >> 5, a = t & 31;
    float v = cng[((rowB + l) * 32 + l) * 32 + a];
    int off = l * (65 - l) / 2;
    cn[off * 33 + a] = v;
    float m = v;
#pragma unroll
    for (int s = 16; s >= 1; s >>= 1) m = fmaxf(m, __shfl_xor(m, s, 32));
    if (a == 0) maxv[off] = m;
  }
  __syncthreads();
  for (int i = 1; i < 32; ++i) {
    int nT = 32 - i;
    int nG = (nT + 15) >> 4;
    // ---- P1: tables + G ----
    {
      int c = t >> 5, j = t & 31;
      float g = -3.0e38f;
      if (c < nT && j < i) {
        int offc = c * (65 - c) / 2;
        int m2 = c + j + 1;
        int rc = m2 * (65 - m2) / 2 + (c + i - m2);
        float bet = maxv[rc];
        int ix = (c << 5) + j;
        Tbet[ix] = bet;
        Tla[ix] = (offc + j) * 33;
        Tra[ix] = rc * 33;
        g = maxv[offc + j] + bet;
      }
#pragma unroll
      for (int s = 16; s >= 1; s >>= 1) g = fmaxf(g, __shfl_xor(g, s, 32));
      if ((t & 31) == 0 && (t >> 5) < nT) G[t >> 5] = g;
    }
    __syncthreads();
    // ---- prefetch out-phase operands for both groups ----
    float nv0 = 0.f, sv0 = 0.f, nv1 = 0.f, sv1 = 0.f;
    if (coR < 16) {
      int c0 = coR & 15;
      if (c0 < nT) {
        nv0 = node[((rowB + c0) * 32 + (c0 + i)) * 32 + aoR];
        sv0 = span[(rowB + c0) * 32 + (c0 + i)];
      }
      int c1 = 16 + c0;
      if (c1 < nT) {
        nv1 = node[((rowB + c1) * 32 + (c1 + i)) * 32 + aoR];
        sv1 = span[(rowB + c1) * 32 + (c1 + i)];
      }
    }
    // ---- group 0 ----
    if (w < nT) p2_cell(w, w, i, ln, cn, Tbet, Tla, Tra, G, Sbf);
    __syncthreads();
    p3_mat(w, ln, Rbf, Sbf, slots);
    __syncthreads();
    if (nG == 2) {
      int cg = 16 + w;
      if (cg < nT) p2_cell(cg, w, i, ln, cn, Tbet, Tla, Tra, G, Sbf);
      out_cell(0, i, nT, w, ln, aoR, coR, slots, G, nv0, sv0, cn);
      __syncthreads();
      p3_mat(w, ln, Rbf, Sbf, slots);
      __syncthreads();
      out_cell(1, i, nT, w, ln, aoR, coR, slots, G, nv1, sv1, cn);
    } else {
      out_cell(0, i, nT, w, ln, aoR, coR, slots, G, nv0, sv0, cn);
    }
    __syncthreads();
    // ---- maxv for the new diagonal ----
    {
      int c = t >> 5, a = t & 31;
      if (c < nT) {
        int ix = c * (65 - c) / 2 + i;
        float m = cn[ix * 33 + a];
#pragma unroll
        for (int s = 16; s >= 1; s >>= 1) m = fmaxf(m, __shfl_xor(m, s, 32));
        if (a == 0) maxv[ix] = m;
      }
    }
    __syncthreads();
  }
  // ---- logits ----
  if (t < 32) {
    int len = 0;
#pragma unroll
    for (int l = 0; l < 32; ++l) len += sm[b * 32 + l];
    int e = len - 1;
    float cv = cn[e * 33 + t] - node[(rowB * 32 + e) * 32 + t];
    out[b * 32 + t] = cv + (rootm[t] - 1.0f) * 1e10f;
  }
}

extern "C" void kernel_launch(void* const* d_in, const int* in_sizes, int n_in,
                              void* d_out, int out_size, void* d_ws, size_t ws_size,
                              hipStream_t stream) {
  const float* ph    = (const float*)d_in[0];
  const float* sh    = (const float*)d_in[1];
  const int*   sm    = (const int*)  d_in[2];
  const float* Wp    = (const float*)d_in[3];
  const float* bp    = (const float*)d_in[4];
  const float* Wn    = (const float*)d_in[5];
  const float* bn    = (const float*)d_in[6];
  const float* Ws    = (const float*)d_in[7];
  const float* bs    = (const float*)d_in[8];
  const float* rs    = (const float*)d_in[9];
  const float* pu    = (const float*)d_in[10];
  const float* rootm = (const float*)d_in[11];
  const float* pm    = (const float*)d_in[12];
  const float* rm    = (const float*)d_in[13];
  const float* pum   = (const float*)d_in[14];
  float* out = (float*)d_out;

  float* ws    = (float*)d_ws;
  float* node  = ws + NODE_OFF;
  float* cng   = ws + CN_OFF;
  float* span  = ws + SPAN_OFF;
  float* D     = ws + D_OFF;
  unsigned short* Rbf = (unsigned short*)(ws + RBF_OFF);
  float* part  = ws + PART_OFF;
  float* partS = ws + PARTS_OFF;

  hipFuncSetAttribute((const void*)k_chain2,
                      hipFuncAttributeMaxDynamicSharedMemorySize, 133632);
  k_pre<<<896, 256, 0, stream>>>(ph, Wn, Ws, sh, Wp, bp, pm, pu, pum, rs, rm,
                                 part, partS, D, Rbf);
  k_node_reduce<<<1024, 256, 0, stream>>>(part, partS, bn, bs, D, node, cng, span);
  k_chain2<<<8, 1024, 133632, stream>>>(node, span, cng, Rbf, sm, rootm, out);
}

// Round 7
// 180.460 us; speedup vs baseline: 1.5329x; 1.5329x over previous
//
#include <hip/hip_runtime.h>
#include <math.h>

// B=8, L=32, H=1024, N=32
// ws layout (floats):
#define NODE_OFF   0          // 8192*32
#define CN_OFF     262144     // 8192*32 (diag rows: chart_diag + 2*node)
#define SPAN_OFF   524288     // 8192
#define D_OFF      532480     // 256*32
#define RBF_OFF    540672     // 32768 halfs: frag-order bf16 exp(rules)
#define PART_OFF   557056     // 4*262144
#define PARTS_OFF  1605632    // 4*8192

typedef short bf16x8 __attribute__((ext_vector_type(8)));
typedef float f32x16 __attribute__((ext_vector_type(16)));

union BFU { unsigned u[4]; bf16x8 v; };

__device__ inline short f2bf(float f) {            // RNE f32->bf16
  union { float f; unsigned u; } v; v.f = f;
  unsigned r = (v.u + 0x7FFFu + ((v.u >> 16) & 1u)) >> 16;
  return (short)r;
}

// Fused front kernel, 896 blocks x 256:
//  0..511: node split-K GEMM   512..767: posnode+D   768..895: Rbf swizzle
__global__ __launch_bounds__(256) void k_pre(
    const float* __restrict__ ph, const float* __restrict__ Wn,
    const float* __restrict__ Ws, const float* __restrict__ sh,
    const float* __restrict__ Wp, const float* __restrict__ bp,
    const float* __restrict__ pmask, const float* __restrict__ pu,
    const float* __restrict__ pum, const float* __restrict__ rs,
    const float* __restrict__ rm, float* __restrict__ part,
    float* __restrict__ partS, float* __restrict__ D,
    unsigned short* __restrict__ Rbf) {
  __shared__ float smem[12672];
  int t = threadIdx.x;
  int bid = blockIdx.x;
  if (bid >= 768) {   // ---- Rbf: frag-order bf16 of exp(masked rules) ----
    int idx = ((bid - 768) << 8) + t;        // [kst(64)][lane(64)][r(8)]
    int kst = idx >> 9, ln = (idx >> 3) & 63, r = idx & 7;
    int a = ln & 31;
    int kp = kst * 16 + ((ln >> 5) << 3) + r;   // k' = p*32+q
    float v = __expf(rs[a * 1024 + kp] + (rm[a * 1024 + kp] - 1.0f) * 1e10f);
    Rbf[idx] = (unsigned short)f2bf(v);
    return;
  }
  if (bid >= 512) {   // ---- posnode + D ----
    float* rowl = smem;
    float* partl = smem + 1024;
    float* posn = smem + 1288;
    int row = bid - 512;
#pragma unroll
    for (int k = 0; k < 4; ++k) rowl[t + 256 * k] = sh[row * 1024 + t + 256 * k];
    __syncthreads();
    int c = t & 31, seg = t >> 5;
    float pacc = 0.f;
    for (int hh = 0; hh < 128; ++hh)
      pacc += rowl[seg * 128 + hh] * Wp[(seg * 128 + hh) * 32 + c];
    partl[seg * 33 + c] = pacc;
    __syncthreads();
    if (t < 32) {
      float s = 0.f;
#pragma unroll
      for (int k = 0; k < 8; ++k) s += partl[k * 33 + t];
      posn[t] = s + bp[t] + (pmask[t] - 1.0f) * 1e10f;
    }
    __syncthreads();
    if (t < 32) {
      float mq = posn[t];
#pragma unroll
      for (int m = 16; m >= 1; m >>= 1) mq = fmaxf(mq, __shfl_xor(mq, m, 32));
      float sum = 0.f;
#pragma unroll 8
      for (int q = 0; q < 32; ++q)
        sum += __expf(pu[t * 32 + q] + (pum[t * 32 + q] - 1.0f) * 1e15f + posn[q] - mq);
      D[row * 32 + t] = mq + __logf(sum);
    }
    return;
  }
  // ---- node split-K GEMM ----
  float (*A)[132] = (float(*)[132])smem;
  float (*Wl)[32] = (float(*)[32])(smem + 8448);
  float* Wsl = smem + 12544;
  int rg = bid >> 2;
  int s = bid & 3;
  int row0 = rg * 64;
  int h0 = s * 256;
  int tr = t >> 3, tc = t & 7;
  int r0 = tr * 2;
  int c = tc * 4;
  float acc[8] = {0.f, 0.f, 0.f, 0.f, 0.f, 0.f, 0.f, 0.f};
  float sp0 = 0.f, sp1 = 0.f;
  for (int hc = 0; hc < 2; ++hc) {
    int hb = h0 + hc * 128;
#pragma unroll
    for (int k = 0; k < 32; ++k) {
      int f = t + 256 * k;
      int rr = f >> 7, hh = f & 127;
      A[rr][hh] = ph[(row0 + rr) * 1024 + hb + hh];
    }
#pragma unroll
    for (int k = 0; k < 16; ++k) {
      int f = t + 256 * k;
      int hh = f >> 5, cc = f & 31;
      Wl[hh][cc] = Wn[(hb + hh) * 32 + cc];
    }
    if (t < 128) Wsl[t] = Ws[hb + t];
    __syncthreads();
#pragma unroll 2
    for (int h = 0; h < 128; ++h) {
      float a0 = A[r0][h], a1 = A[r0 + 1][h];
      float4 w = *(const float4*)&Wl[h][c];
      acc[0] += a0 * w.x; acc[1] += a0 * w.y; acc[2] += a0 * w.z; acc[3] += a0 * w.w;
      acc[4] += a1 * w.x; acc[5] += a1 * w.y; acc[6] += a1 * w.z; acc[7] += a1 * w.w;
      if (tc == 0) { float wv = Wsl[h]; sp0 += a0 * wv; sp1 += a1 * wv; }
    }
    __syncthreads();
  }
  int row = row0 + r0;
  float* po = part + s * 262144;
  *(float4*)&po[row * 32 + c] = make_float4(acc[0], acc[1], acc[2], acc[3]);
  *(float4*)&po[(row + 1) * 32 + c] = make_float4(acc[4], acc[5], acc[6], acc[7]);
  if (tc == 0) {
    partS[s * 8192 + row] = sp0;
    partS[s * 8192 + row + 1] = sp1;
  }
}

__global__ __launch_bounds__(256) void k_node_reduce(
    const float* __restrict__ part, const float* __restrict__ partS,
    const float* __restrict__ bn, const float* __restrict__ bs,
    const float* __restrict__ D, float* __restrict__ node,
    float* __restrict__ cng, float* __restrict__ span) {
  int t = threadIdx.x;
  int row = blockIdx.x * 8 + (t >> 5);
  int c = t & 31;
  float v = bn[c];
#pragma unroll
  for (int s = 0; s < 4; ++s) v += part[s * 262144 + row * 32 + c];
  node[row * 32 + c] = v;
  int l = (row >> 5) & 31, m = row & 31;
  if (l == m)
    cng[row * 32 + c] = v + D[(row >> 5) * 32 + c] + v;   // chart_diag + node
  if (c == 0) {
    float sp = bs[0];
#pragma unroll
    for (int s = 0; s < 4; ++s) sp += partS[s * 8192 + row];
    span[row] = sp;
  }
}

// One block per batch; chart kept as NORMALIZED X = exp(cn - rowmax) in LDS
// (transposed [symbol][cellidx]); per-stage: P1 scalar tables -> P2 per-wave
// S-MFMA -> P3 32-cell-wide rule matvec (MFMA) -> out -> renormalize.
// Dynamic LDS 160192 B:
//   Xt    f32[32][529]   @0        (X, transposed, stride 529)
//   Sb    32 slots*2052B @67712    (bf16 S, XOR-swizzled)
//   slots f32[4][1024]   @133376
//   T2    int2[32][32]   @149760   ({scl, right-cell word offset})
//   maxv  f32[528]       @157952
//   G     f32[32]        @160064
__global__ __launch_bounds__(1024) void k_chain3(
    const float* __restrict__ node, const float* __restrict__ span,
    const float* __restrict__ cng, const unsigned short* __restrict__ Rbf,
    const int* __restrict__ sm, const float* __restrict__ rootm,
    float* __restrict__ out) {
  extern __shared__ char lds[];
  float* Xt = (float*)lds;
  char* Sb = lds + 67712;
  float* slots = (float*)(lds + 133376);
  int2* T2 = (int2*)(lds + 149760);
  float* maxv = (float*)(lds + 157952);
  float* G = (float*)(lds + 160064);
  const int t = threadIdx.x;
  const int b = blockIdx.x;
  const int w = t >> 6, ln = t & 63;
  const int pq = ln & 31, hi = ln >> 5, jb = hi << 3;
  const int rowB = b * 32;
  const int a_o = (w & 3) + ((w >> 2) << 3) + (hi << 2);  // C/D row (reg=w)
  const int c_o = pq;                                      // C/D col (cell)

  // ---- init: diagonal cells -> X, maxv ----
  {
    int l = t >> 5, a = t & 31;
    float v = cng[((rowB + l) * 32 + l) * 32 + a];
    float m = v;
#pragma unroll
    for (int s = 16; s >= 1; s >>= 1) m = fmaxf(m, __shfl_xor(m, s, 32));
    int off = l * (65 - l) / 2;
    Xt[a * 529 + off] = __expf(v - m);
    if (a == 0) maxv[off] = m;
  }
  __syncthreads();

  for (int i = 1; i < 32; ++i) {
    const int nT = 32 - i;
    // ---- out-phase global prefetch ----
    float nv = 0.f, sv = 0.f;
    if (c_o < nT) {
      int gr = (rowB + c_o) * 32 + (c_o + i);
      nv = node[gr * 32 + a_o];
      sv = span[gr];
    }
    // ---- P1: per-(cell,j) scalar tables + G ----
    {
      int c = t >> 5, j = t & 31;
      bool on = (c < nT) && (j < i);
      float gj = -3.0e38f; int rc = 0;
      if (on) {
        int m2 = c + j + 1;
        rc = m2 * (65 - m2) / 2 + (i - 1 - j);
        gj = maxv[c * (65 - c) / 2 + j] + maxv[rc];
      }
      float gm = gj;
#pragma unroll
      for (int s = 16; s >= 1; s >>= 1) gm = fmaxf(gm, __shfl_xor(gm, s, 32));
      if (c < nT) {
        float sc = on ? __expf(gj - gm) : 0.f;
        T2[(c << 5) + j] = make_int2(__float_as_int(sc), on ? rc : 0);
        if (j == 0) G[c] = gm;
      }
    }
    __syncthreads();
    // ---- P2: wave w handles cells w and 16+w; S = sum_j scl*Xl (x) Xr ----
    for (int half = 0; half < 2; ++half) {
      int cg = (half << 4) + w;
      if (cg >= nT) break;                       // wave-uniform
      const float* xlb = Xt + pq * 529 + cg * (65 - cg) / 2;
      const float* xrr = Xt + pq * 529;
      f32x16 Sacc = {};
#pragma unroll
      for (int kk = 0; kk < 2; ++kk) {
        if (kk == 1 && i <= 16) break;
        int j0 = (kk << 4);
        float xl[8], xr[8], sc[8];
#pragma unroll
        for (int r = 0; r < 8; ++r) {
          int2 e = T2[(cg << 5) + j0 + jb + r];
          sc[r] = __int_as_float(e.x);
          xr[r] = xrr[e.y];
          xl[r] = xlb[j0 + jb + r];
        }
        BFU ua, ub;
#pragma unroll
        for (int r2 = 0; r2 < 4; ++r2) {
          unsigned al = (unsigned short)f2bf(sc[2 * r2] * xl[2 * r2]);
          unsigned ah = (unsigned short)f2bf(sc[2 * r2 + 1] * xl[2 * r2 + 1]);
          ua.u[r2] = al | (ah << 16);
          unsigned bl = (unsigned short)f2bf(xr[2 * r2]);
          unsigned bh = (unsigned short)f2bf(xr[2 * r2 + 1]);
          ub.u[r2] = bl | (bh << 16);
        }
        Sacc = __builtin_amdgcn_mfma_f32_32x32x16_bf16(ua.v, ub.v, Sacc, 0, 0, 0);
      }
      // store S bf16, XOR-swizzled (word = p*16+q/2 ^ ((q>>3&1)<<4) ^ ((p>>2&1)<<2))
      char* sbp = Sb + cg * 2052;
#pragma unroll
      for (int rr = 0; rr < 16; ++rr) {
        int p = (rr & 3) + ((rr >> 2) << 3) + (hi << 2);
        int wd = (((p << 4) + (pq >> 1)) ^ (((pq >> 3) & 1) << 4)) ^ (((p >> 2) & 1) << 2);
        *(unsigned short*)(sbp + wd * 4 + ((pq & 1) << 1)) = (unsigned short)f2bf(Sacc[rr]);
      }
    }
    __syncthreads();
    // ---- P3: inner = R * S^T, 32 cells wide, 4 waves k-split ----
    if (w < 4) {
      f32x16 C0 = {}, C1 = {};
#pragma unroll
      for (int tt = 0; tt < 16; ++tt) {
        int kst = (w << 4) + tt;
        bf16x8 ra = *(const bf16x8*)(Rbf + (kst << 9) + (ln << 3));
        int ko = (kst << 1) + hi;
        int p = ko >> 2, o = ko & 3;
        int wd = (((p << 4) + (o << 2)) ^ ((o & 1) << 4)) ^ (((p >> 2) & 1) << 2);
        const char* sp = Sb + pq * 2052 + wd * 4;
        BFU ub;
        ub.u[0] = *(const unsigned*)sp;
        ub.u[1] = *(const unsigned*)(sp + 4);
        ub.u[2] = *(const unsigned*)(sp + 8);
        ub.u[3] = *(const unsigned*)(sp + 12);
        if (tt & 1) C1 = __builtin_amdgcn_mfma_f32_32x32x16_bf16(ra, ub.v, C1, 0, 0, 0);
        else        C0 = __builtin_amdgcn_mfma_f32_32x32x16_bf16(ra, ub.v, C0, 0, 0, 0);
      }
      float* sl = slots + (w << 10);
#pragma unroll
      for (int rr = 0; rr < 16; ++rr) sl[(rr << 6) + ln] = C0[rr] + C1[rr];
    }
    __syncthreads();
    // ---- out: cn_new = G + log(pt) + 2*node + span (raw, pre-normalization) ----
    if (c_o < nT) {
      float pt = slots[(w << 6) + ln] + slots[1024 + (w << 6) + ln] +
                 slots[2048 + (w << 6) + ln] + slots[3072 + (w << 6) + ln];
      float cnv = G[c_o] + __logf(pt) + nv + nv + sv;
      Xt[a_o * 529 + c_o * (65 - c_o) / 2 + i] = cnv;
    }
    __syncthreads();
    // ---- renormalize new cells: X = exp(cn - rowmax), maxv = rowmax ----
    {
      int c = t >> 5, a = t & 31;
      if (c < nT) {
        int ix = c * (65 - c) / 2 + i;
        float val = Xt[a * 529 + ix];
        float m = val;
#pragma unroll
        for (int s = 16; s >= 1; s >>= 1) m = fmaxf(m, __shfl_xor(m, s, 32));
        Xt[a * 529 + ix] = __expf(val - m);
        if (a == 0) maxv[ix] = m;
      }
    }
    __syncthreads();
  }
  // ---- logits ----
  if (t < 32) {
    int len = 0;
#pragma unroll
    for (int l = 0; l < 32; ++l) len += sm[b * 32 + l];
    int e = len - 1;   // cell (0, e) has triangular index e
    float cv = maxv[e] + __logf(Xt[t * 529 + e]) - node[(rowB * 32 + e) * 32 + t];
    out[b * 32 + t] = cv + (rootm[t] - 1.0f) * 1e10f;
  }
}

extern "C" void kernel_launch(void* const* d_in, const int* in_sizes, int n_in,
                              void* d_out, int out_size, void* d_ws, size_t ws_size,
                              hipStream_t stream) {
  const float* ph    = (const float*)d_in[0];
  const float* sh    = (const float*)d_in[1];
  const int*   sm    = (const int*)  d_in[2];
  const float* Wp    = (const float*)d_in[3];
  const float* bp    = (const float*)d_in[4];
  const float* Wn    = (const float*)d_in[5];
  const float* bn    = (const float*)d_in[6];
  const float* Ws    = (const float*)d_in[7];
  const float* bs    = (const float*)d_in[8];
  const float* rs    = (const float*)d_in[9];
  const float* pu    = (const float*)d_in[10];
  const float* rootm = (const float*)d_in[11];
  const float* pm    = (const float*)d_in[12];
  const float* rm    = (const float*)d_in[13];
  const float* pum   = (const float*)d_in[14];
  float* out = (float*)d_out;

  float* ws    = (float*)d_ws;
  float* node  = ws + NODE_OFF;
  float* cng   = ws + CN_OFF;
  float* span  = ws + SPAN_OFF;
  float* D     = ws + D_OFF;
  unsigned short* Rbf = (unsigned short*)(ws + RBF_OFF);
  float* part  = ws + PART_OFF;
  float* partS = ws + PARTS_OFF;

  hipFuncSetAttribute((const void*)k_chain3,
                      hipFuncAttributeMaxDynamicSharedMemorySize, 160192);
  k_pre<<<896, 256, 0, stream>>>(ph, Wn, Ws, sh, Wp, bp, pm, pu, pum, rs, rm,
                                 part, partS, D, Rbf);
  k_node_reduce<<<1024, 256, 0, stream>>>(part, partS, bn, bs, D, node, cng, span);
  k_chain3<<<8, 1024, 160192, stream>>>(node, span, cng, Rbf, sm, rootm, out);
}